// Round 9
// baseline (253.743 us; speedup 1.0000x reference)
//
#include <hip/hip_runtime.h>
#include <math.h>

#define BATCH 64
#define NN 512
#define MM 512
#define DD 128
#define BIGF 1e30f
#define KLOG2E 1.442695040888963f
#define LN2F   0.693147180559945f
#define BIGK   (BIGF * KLOG2E)

typedef __attribute__((ext_vector_type(2))) float f32x2;

// ---------------------------------------------------------------------------
// Kernel 1: squared row norms of X (B*N rows) and Y (B*M rows).
// ---------------------------------------------------------------------------
__global__ __launch_bounds__(256) void sqnorm_kernel(const float* __restrict__ X,
                                                     const float* __restrict__ Y,
                                                     float* __restrict__ x2,
                                                     float* __restrict__ y2) {
    int row  = blockIdx.x * 4 + (threadIdx.x >> 6);
    int lane = threadIdx.x & 63;
    const float* src;
    float* dst;
    int r;
    if (row < BATCH * NN) { src = X; dst = x2; r = row; }
    else                  { src = Y; dst = y2; r = row - BATCH * NN; }
    const float* p = src + (size_t)r * DD;
    float a = p[lane];
    float b = p[lane + 64];
    float s = a * a + b * b;
    #pragma unroll
    for (int m = 32; m >= 1; m >>= 1) s += __shfl_xor(s, m, 64);
    if (lane == 0) dst[r] = s;
}

// ---------------------------------------------------------------------------
// Kernel 2: CT[b,j,i] = (x2[b,i] + y2[b,j] - 2*dot(X,Y)) * (log2e / D)
// Pre-scaled by log2(e): DTW kernel runs natively in base-2 domain.
// ---------------------------------------------------------------------------
#define TM 64

__global__ __launch_bounds__(256) void cost_kernel(const float* __restrict__ X,
                                                   const float* __restrict__ Y,
                                                   const float* __restrict__ x2,
                                                   const float* __restrict__ y2,
                                                   float* __restrict__ CT) {
    __shared__ float Xs[TM * DD];
    __shared__ float Ys[TM * DD];
    int b  = blockIdx.z;
    int ti = blockIdx.y * TM;
    int tj = blockIdx.x * TM;
    int t  = threadIdx.x;
    const float* Xb = X + ((size_t)b * NN + ti) * DD;
    const float* Yb = Y + ((size_t)b * MM + tj) * DD;

    int k4l = t & 31;
    int rl  = t >> 5;
    #pragma unroll
    for (int it = 0; it < 8; ++it) {
        int r  = rl + it * 8;
        int sw = r * 32 + (k4l ^ ((r >> 2) & 7));
        *(float4*)&Xs[4 * sw] = *(const float4*)&Xb[(size_t)r * DD + 4 * k4l];
        *(float4*)&Ys[4 * sw] = *(const float4*)&Yb[(size_t)r * DD + 4 * k4l];
    }
    __syncthreads();

    int tx = t & 15;
    int ty = t >> 4;
    float acc[4][4] = {};
    #pragma unroll 4
    for (int k4 = 0; k4 < 32; ++k4) {
        float4 xa[4], yb[4];
        int kx = k4 ^ (tx & 7);
        int ky = k4 ^ ty;
        #pragma unroll
        for (int m = 0; m < 4; ++m)
            xa[m] = *(const float4*)&Xs[4 * ((tx * 4 + m) * 32 + kx)];
        #pragma unroll
        for (int n = 0; n < 4; ++n)
            yb[n] = *(const float4*)&Ys[4 * ((ty * 4 + n) * 32 + ky)];
        #pragma unroll
        for (int m = 0; m < 4; ++m)
            #pragma unroll
            for (int n = 0; n < 4; ++n)
                acc[m][n] += xa[m].x * yb[n].x + xa[m].y * yb[n].y
                           + xa[m].z * yb[n].z + xa[m].w * yb[n].w;
    }

    const float inv = KLOG2E / (float)DD;
    int i0 = ti + tx * 4;
    float4 xx = *(const float4*)&x2[b * NN + i0];
    #pragma unroll
    for (int n = 0; n < 4; ++n) {
        int j = tj + ty * 4 + n;
        float yy = y2[b * MM + j];
        float4 o;
        o.x = (xx.x + yy - 2.0f * acc[0][n]) * inv;
        o.y = (xx.y + yy - 2.0f * acc[1][n]) * inv;
        o.z = (xx.z + yy - 2.0f * acc[2][n]) * inv;
        o.w = (xx.w + yy - 2.0f * acc[3][n]) * inv;
        *(float4*)&CT[((size_t)b * MM + j) * NN + i0] = o;
    }
}

// ---------------------------------------------------------------------------
// Kernel 3: 4-wave soft-DTW, log-free (s,q) carry, K=16 CHUNKED handoff.
// Thread p owns rows 2p,2p+1; column j = s - (p + 15*(p>>6)) at step s.
// Inter-wave skew E=15 => wave w consumes wave w-1's lane-63 bottoms a full
// chunk (K=16 steps) late: producer writes per-step into buf[I&1][w][sig];
// consumer lane-0 broadcast-reads slot sig of the STABLE buf[(I-1)&1][w-1]
// (prefetched 1 step ahead; sig=0's diag = carried slot-15 via ub->db rotate).
// ONE lgkmcnt(0)+s_barrier per 16 steps (was per step in r8: ~350cyc/step).
// Global loads: asm depth-8 ring, vmcnt(7); 16 steps/iter aligns slots mod 8.
// (s,q) update per cell: m=min3(scales), 3 exps, 2fma+mul, NO log (resolve
// once at the end). Renorm q per iteration via exponent extraction.
// Cell (0,0): w0/l0/s0 diag pair seeded (0,1) -> v = c exactly.
// ---------------------------------------------------------------------------
#define RING 8
#define KCH 16
#define ESK 15
#define NITER 51   // 816 steps >= 512 + 255 + 45 + 1

__global__ __launch_bounds__(256) void sdtw_kernel(const float* __restrict__ CT,
                                                   float* __restrict__ part) {
    int b = blockIdx.x;
    int p = threadIdx.x;          // 0..255
    int l = p & 63;
    int w = p >> 6;
    int wm1 = (w == 0) ? 0 : (w - 1);
    int off = p + ESK * w;        // column skew: j = s - off
    const char* CbL = (const char*)CT + (size_t)b * (MM * NN * 4) + p * 8;

    __shared__ f32x2 buf[2][4][KCH];   // [parity][wave][slot], 1 KB

    if (p < 128) ((f32x2*)buf)[p] = f32x2{BIGK, 1.0f};
    __syncthreads();

    float ps0 = BIGK, pq0 = 1.0f;      // row 2p   pair at col j-1
    float ps1 = BIGK, pq1 = 1.0f;      // row 2p+1 pair at col j-1
    float nbc_s = BIGK, nbc_q = 1.0f;  // shfl up-pair   (lanes 1..63)
    float nbp_s = BIGK, nbp_q = 1.0f;  // shfl diag-pair (lanes 1..63)
    f32x2 ub = {BIGK, 1.0f};           // lane0 up pair   (slot sig)
    f32x2 db = {BIGK, 1.0f};           // lane0 diag pair (slot sig-1)
    f32x2 nxt = {BIGK, 1.0f};

    f32x2 r0, r1, r2, r3, r4, r5, r6, r7;

#define LOADP(REG, COL) do {                                                   \
    const char* pa_ = CbL + (((unsigned)(COL)) & 511u) * 2048u;                \
    asm volatile("global_load_dwordx2 %0, %1, off"                             \
                 : "=&v"(REG) : "v"(pa_) : "memory");                          \
} while (0)

    LOADP(r0, 0 - off); LOADP(r1, 1 - off); LOADP(r2, 2 - off);
    LOADP(r3, 3 - off); LOADP(r4, 4 - off); LOADP(r5, 5 - off);
    LOADP(r6, 6 - off); LOADP(r7, 7 - off);

#define STEP(REG, SIG) do {                                                    \
    int s_ = sbase + (SIG);                                                    \
    int j_ = s_ - off;                                                         \
    asm volatile("s_waitcnt vmcnt(7)" ::: "memory");                           \
    __builtin_amdgcn_sched_barrier(0);                                         \
    f32x2 cc = REG;                                                            \
    db = ub; ub = nxt;                                                         \
    if ((SIG) < KCH - 1) nxt = rb[(SIG) + 1];                                  \
    float su, qu, sd2, qd;                                                     \
    if (l == 0) {                                                              \
        if (w == 0) { su = BIGK; qu = 1.0f;                                    \
                      sd2 = (s_ == 0) ? 0.0f : BIGK; qd = 1.0f; }              \
        else        { su = ub.x; qu = ub.y; sd2 = db.x; qd = db.y; }           \
    } else { su = nbc_s; qu = nbc_q; sd2 = nbp_s; qd = nbp_q; }                \
    if ((unsigned)j_ < 512u) {                                                 \
        float lAs = ps0, lAq = pq0;                                            \
        float m1;                                                              \
        asm("v_min3_f32 %0, %1, %2, %3" : "=v"(m1) : "v"(su), "v"(lAs), "v"(sd2)); \
        float eu, el, ed;                                                      \
        asm("v_exp_f32 %0, %1" : "=v"(eu) : "v"(m1 - su));                     \
        asm("v_exp_f32 %0, %1" : "=v"(el) : "v"(m1 - lAs));                    \
        asm("v_exp_f32 %0, %1" : "=v"(ed) : "v"(m1 - sd2));                    \
        float qA = __builtin_fmaf(qu, eu, __builtin_fmaf(lAq, el, qd * ed));   \
        float sA = cc.x + m1;                                                  \
        float m2;                                                              \
        asm("v_min3_f32 %0, %1, %2, %3" : "=v"(m2) : "v"(sA), "v"(ps1), "v"(lAs)); \
        float fu, fl, fd;                                                      \
        asm("v_exp_f32 %0, %1" : "=v"(fu) : "v"(m2 - sA));                     \
        asm("v_exp_f32 %0, %1" : "=v"(fl) : "v"(m2 - ps1));                    \
        asm("v_exp_f32 %0, %1" : "=v"(fd) : "v"(m2 - lAs));                    \
        float qB = __builtin_fmaf(qA, fu, __builtin_fmaf(pq1, fl, lAq * fd));  \
        float sB = cc.y + m2;                                                  \
        ps0 = sA; pq0 = qA; ps1 = sB; pq1 = qB;                                \
    }                                                                          \
    float shs_ = __shfl_up(ps1, 1);                                            \
    float shq_ = __shfl_up(pq1, 1);                                            \
    nbp_s = nbc_s; nbp_q = nbc_q;                                              \
    nbc_s = shs_;  nbc_q = shq_;                                               \
    if (l == 63) wb[SIG] = f32x2{ps1, pq1};                                    \
    LOADP(REG, s_ + RING - off);                                               \
} while (0)

#define RENORM(S, Q) do {                                                      \
    int e_ = (__float_as_int(Q) >> 23) - 127;                                  \
    Q = __int_as_float(__float_as_int(Q) - (e_ << 23));                        \
    S = S - (float)e_;                                                         \
} while (0)

    for (int I = 0; I < NITER; ++I) {
        asm volatile("s_waitcnt lgkmcnt(0)" ::: "memory");
        __builtin_amdgcn_s_barrier();
        asm volatile("" ::: "memory");
        const f32x2* rb = &buf[(I + 1) & 1][wm1][0];  // written in iter I-1
        f32x2*       wb = &buf[I & 1][w][0];          // read    in iter I+1
        nxt = rb[0];
        int sbase = I * KCH;
        STEP(r0, 0);  STEP(r1, 1);  STEP(r2, 2);  STEP(r3, 3);
        STEP(r4, 4);  STEP(r5, 5);  STEP(r6, 6);  STEP(r7, 7);
        STEP(r0, 8);  STEP(r1, 9);  STEP(r2, 10); STEP(r3, 11);
        STEP(r4, 12); STEP(r5, 13); STEP(r6, 14); STEP(r7, 15);
        RENORM(ps0, pq0);
        RENORM(ps1, pq1);
    }

    if (p == 255) {   // cell (511,511): single resolve
        float lg;
        asm("v_log_f32 %0, %1" : "=v"(lg) : "v"(pq1));
        part[b] = (ps1 - lg) * LN2F;
    }
#undef STEP
#undef LOADP
#undef RENORM
}

// ---------------------------------------------------------------------------
// Kernel 4: one-wave deterministic reduction. out = sum_b(R_b) / (B * N)
// ---------------------------------------------------------------------------
__global__ __launch_bounds__(64) void reduce_kernel(const float* __restrict__ part,
                                                    float* __restrict__ out) {
    int l = threadIdx.x;
    float v = part[l];
    #pragma unroll
    for (int m = 32; m >= 1; m >>= 1) v += __shfl_xor(v, m, 64);
    if (l == 0) out[0] = v / (float)(BATCH * NN);
}

// ---------------------------------------------------------------------------
extern "C" void kernel_launch(void* const* d_in, const int* in_sizes, int n_in,
                              void* d_out, int out_size, void* d_ws, size_t ws_size,
                              hipStream_t stream) {
    const float* X = (const float*)d_in[0];
    const float* Y = (const float*)d_in[1];
    float* out = (float*)d_out;

    char* ws = (char*)d_ws;
    float* CT   = (float*)ws;                                   // 64 MB
    float* x2   = (float*)(ws + (size_t)BATCH * NN * MM * 4);   // 128 KB
    float* y2   = x2 + BATCH * NN;                              // 128 KB
    float* part = y2 + BATCH * MM;                              // 256 B

    sqnorm_kernel<<<(BATCH * (NN + MM)) / 4, 256, 0, stream>>>(X, Y, x2, y2);

    dim3 g(MM / TM, NN / TM, BATCH);
    cost_kernel<<<g, 256, 0, stream>>>(X, Y, x2, y2, CT);

    sdtw_kernel<<<BATCH, 256, 0, stream>>>(CT, part);

    reduce_kernel<<<1, 64, 0, stream>>>(part, out);
}